// Round 6
// baseline (252.722 us; speedup 1.0000x reference)
//
#include <hip/hip_runtime.h>

typedef unsigned short u16;
typedef unsigned int u32;
typedef __attribute__((ext_vector_type(8))) short bf16x8;
typedef __attribute__((ext_vector_type(4))) float f32x4;

#define HID 2048
#define S_LEN 1024
#define BATCH 2
#define G_KV 8
#define R_REP 4
#define HD 64
#define NQKV 3072  // 2048 q + 512 k + 512 v

__device__ __forceinline__ u16 f2bf(float f) {
    union { u32 u; float ff; } x; x.ff = f;
    u32 u = x.u;
    u += 0x7FFFu + ((u >> 16) & 1u);
    return (u16)(u >> 16);
}

__device__ __forceinline__ void gload_lds16(const void* g, void* l) {
    __builtin_amdgcn_global_load_lds((const __attribute__((address_space(1))) void*)g,
                                     (__attribute__((address_space(3))) void*)l,
                                     16, 0, 0);
}

// ------- Fused prep: cvt_x | transpose_qkv | transpose_cvt(Wo) in one launch -------
// blocks [0,2048): x fp32 -> bf16 (Xb)
// blocks [2048,8192): {Wq|Wk|Wv} fp32 [2048][*] -> WqkvT bf16 [3072][2048]
// blocks [8192,12288): Wo fp32 [2048][2048] -> WoT bf16 [2048][2048]
__global__ __launch_bounds__(256) void prep(const float* __restrict__ x,
                                            const float* __restrict__ Wq,
                                            const float* __restrict__ Wk,
                                            const float* __restrict__ Wv,
                                            const float* __restrict__ Wo,
                                            u16* __restrict__ Xb,
                                            u16* __restrict__ WqkvT,
                                            u16* __restrict__ WoT) {
    __shared__ float tile[32][33];
    int bid = blockIdx.x, tid = threadIdx.x;

    if (bid < 2048) {
        // cvt_x
        int i = (bid * 256 + tid) * 8;
        float4 a = *(const float4*)(x + i);
        float4 b = *(const float4*)(x + i + 4);
        u16 t[8] = {f2bf(a.x), f2bf(a.y), f2bf(a.z), f2bf(a.w),
                    f2bf(b.x), f2bf(b.y), f2bf(b.z), f2bf(b.w)};
        *(uint4*)(Xb + i) = *(const uint4*)t;
        return;
    }

    int tx = tid & 31, ty = tid >> 5;
    if (bid < 8192) {
        // transpose_qkv
        int local = bid - 2048;
        int n0 = (local % 96) * 32, k0 = (local / 96) * 32;
        const float* in; int N, nc0;
        if (n0 < 2048)      { in = Wq; N = 2048; nc0 = n0; }
        else if (n0 < 2560) { in = Wk; N = 512;  nc0 = n0 - 2048; }
        else                { in = Wv; N = 512;  nc0 = n0 - 2560; }
#pragma unroll
        for (int j = 0; j < 4; ++j)
            tile[ty + j * 8][tx] = in[(size_t)(k0 + ty + j * 8) * N + nc0 + tx];
        __syncthreads();
#pragma unroll
        for (int j = 0; j < 4; ++j)
            WqkvT[(size_t)(n0 + ty + j * 8) * 2048 + k0 + tx] = f2bf(tile[tx][ty + j * 8]);
        return;
    }

    // transpose_cvt Wo [2048][2048] -> WoT
    {
        int local = bid - 8192;
        int n0 = (local & 63) * 32, k0 = (local >> 6) * 32;
#pragma unroll
        for (int j = 0; j < 4; ++j)
            tile[ty + j * 8][tx] = Wo[(size_t)(k0 + ty + j * 8) * 2048 + n0 + tx];
        __syncthreads();
#pragma unroll
        for (int j = 0; j < 4; ++j)
            WoT[(size_t)(n0 + ty + j * 8) * 2048 + k0 + tx] = f2bf(tile[tx][ty + j * 8]);
    }
}

// ------- QKV GEMM: BM=64 BN=128 BK=64, 768 blocks (3/CU), dbuf, one barrier per
//         K64-step (32 sync points, was 64). Linear LDS (conflicts proven hidden).
__global__ __launch_bounds__(256) void gemm_qkv(const u16* __restrict__ Xb,
                                                const u16* __restrict__ WT,
                                                const float* __restrict__ bq,
                                                const float* __restrict__ bk,
                                                const float* __restrict__ bv,
                                                u16* __restrict__ qb,
                                                u16* __restrict__ kb,
                                                u16* __restrict__ vb) {
    __shared__ __align__(16) u16 As[2][64 * 64];    // 16 KiB
    __shared__ __align__(16) u16 Bs[2][128 * 64];   // 32 KiB
    int tid = threadIdx.x;
    int w = tid >> 6, lane = tid & 63, quad = lane >> 4, l16 = lane & 15;
    int m0 = blockIdx.y * 64, n0 = blockIdx.x * 128;
    int wr = (w >> 1) * 32, wc = (w & 1) * 64;   // wave tile 32x64
    int srow = lane >> 3, scol = (lane & 7) * 8;  // staging: 8 rows x 128B per wave-load

    // staging sources (k-advance += 64)
    const u16* aP0 = &Xb[(size_t)(m0 + w * 16 + srow) * 2048 + scol];
    const u16* aP1 = aP0 + (size_t)8 * 2048;
    const u16* bP  = &WT[(size_t)(n0 + w * 32 + srow) * 2048 + scol];

    f32x4 acc[2][4];
#pragma unroll
    for (int i = 0; i < 2; ++i)
#pragma unroll
        for (int j = 0; j < 4; ++j) acc[i][j] = (f32x4){0.f, 0.f, 0.f, 0.f};

    // prologue: stage tile 0 into buffer 0 (6 loads/wave)
    gload_lds16(aP0, &As[0][(w * 16) * 64]);
    gload_lds16(aP1, &As[0][(w * 16 + 8) * 64]);
#pragma unroll
    for (int j = 0; j < 4; ++j)
        gload_lds16(bP + (size_t)(j * 8) * 2048, &Bs[0][(w * 32 + j * 8) * 64]);
    __syncthreads();

    int cur = 0;
    for (int k0 = 0; k0 < 2048; k0 += 64) {
        int kn = k0 + 64;
        if (kn < 2048) {
            // issue next-tile stage FIRST: flies during this tile's ds_read+MFMA
            gload_lds16(aP0 + kn, &As[cur ^ 1][(w * 16) * 64]);
            gload_lds16(aP1 + kn, &As[cur ^ 1][(w * 16 + 8) * 64]);
#pragma unroll
            for (int j = 0; j < 4; ++j)
                gload_lds16(bP + (size_t)(j * 8) * 2048 + kn, &Bs[cur ^ 1][(w * 32 + j * 8) * 64]);
        }
#pragma unroll
        for (int kk = 0; kk < 2; ++kk) {
            bf16x8 af[2], bfr[4];
#pragma unroll
            for (int mt = 0; mt < 2; ++mt)
                af[mt] = *(const bf16x8*)&As[cur][(wr + mt * 16 + l16) * 64 + kk * 32 + quad * 8];
#pragma unroll
            for (int nt = 0; nt < 4; ++nt)
                bfr[nt] = *(const bf16x8*)&Bs[cur][(wc + nt * 16 + l16) * 64 + kk * 32 + quad * 8];
#pragma unroll
            for (int mt = 0; mt < 2; ++mt)
#pragma unroll
                for (int nt = 0; nt < 4; ++nt)
                    acc[mt][nt] = __builtin_amdgcn_mfma_f32_16x16x32_bf16(af[mt], bfr[nt], acc[mt][nt], 0, 0, 0);
        }
        __syncthreads();
        cur ^= 1;
    }

#pragma unroll
    for (int nt = 0; nt < 4; ++nt) {
        int n = n0 + wc + nt * 16 + l16;
        float bias;
        if (n < 2048) bias = bq[n];
        else if (n < 2560) bias = bk[n - 2048];
        else bias = bv[n - 2560];
#pragma unroll
        for (int mt = 0; mt < 2; ++mt) {
#pragma unroll
            for (int reg = 0; reg < 4; ++reg) {
                int m = m0 + wr + mt * 16 + quad * 4 + reg;
                float val = acc[mt][nt][reg] + bias;
                int b = m >> 10, s = m & 1023;
                if (n < 2048) {
                    int g = n >> 8, r = (n >> 6) & 3, d = n & 63;
                    qb[((((size_t)(b * G_KV + g) * R_REP + r) * S_LEN) + s) * HD + d] = f2bf(val * 0.125f);
                } else if (n < 2560) {
                    int n2 = n - 2048, g = n2 >> 6, d = n2 & 63;
                    kb[(((size_t)(b * G_KV + g) * S_LEN) + s) * HD + d] = f2bf(val);
                } else {
                    int n2 = n - 2560, g = n2 >> 6, d = n2 & 63;
                    vb[(((size_t)(b * G_KV + g) * HD + d) * S_LEN) + s] = f2bf(val);  // V^T
                }
            }
        }
    }
}

// ------- Attention: MFMA flash, S^T orientation (S^T = K·Q^T); raw-mask direct reads -------
__global__ __launch_bounds__(256) void attn_mfma(const u16* __restrict__ qbuf,
                                                 const u16* __restrict__ kbuf,
                                                 const u16* __restrict__ vtbuf,
                                                 const float* __restrict__ mask,
                                                 u16* __restrict__ aout) {
    __shared__ __align__(16) u16 Ks[64 * 72];   // [key][dim]
    __shared__ __align__(16) u16 Vs[64 * 72];   // [dim][key]
    __shared__ __align__(16) u16 Ps[64 * 72];   // [q][key] bf16 (wave-private strips)
    __shared__ float l_lds[64];

    int d = blockIdx.x;
    int xcd = d & 7, j = d >> 3;
    int pr = xcd * 2 + (j >> 6);          // (b,g) pair 0..15
    int r = (j >> 4) & 3, qblk = j & 15;
    int b = pr >> 3, g = pr & 7;

    int tid = threadIdx.x;
    int w = tid >> 6, lane = tid & 63, quad = lane >> 4, l16 = lane & 15;
    int s0 = qblk * 64;
    int q = w * 16 + l16;                 // this lane's softmax q-row

    const u16* qrow = qbuf +
        ((((size_t)(b * G_KV + g) * R_REP + r) * S_LEN) + s0 + q) * HD;
    bf16x8 qf0 = *(const bf16x8*)(qrow + quad * 8);
    bf16x8 qf1 = *(const bf16x8*)(qrow + 32 + quad * 8);

    f32x4 o_acc[4];
#pragma unroll
    for (int i = 0; i < 4; ++i) o_acc[i] = (f32x4){0.f, 0.f, 0.f, 0.f};
    float l_part = 0.f;

    const u16* kbase  = kbuf  + (size_t)(b * G_KV + g) * S_LEN * HD;
    const u16* vtbase = vtbuf + (size_t)(b * G_KV + g) * HD * S_LEN;
    // raw mask, fragment-aligned direct reads:
    // mc[mt][rg] = mask[b][s0+q][kt*64 + mt*16 + quad*4 + rg]  (16B-aligned f32x4)
    const float* mrow = mask + ((size_t)b * S_LEN + s0 + q) * S_LEN + quad * 4;

    int srow = tid >> 2, sc = (tid & 3) * 16;

    // prologue: prefetch tile 0
    uint4 kp0, kp1, vp0, vp1;
    f32x4 mc[4], mn[4];
    {
        const u16* kr = kbase + (size_t)srow * HD + sc;
        kp0 = *(const uint4*)kr; kp1 = *(const uint4*)(kr + 8);
        const u16* vr = vtbase + (size_t)srow * S_LEN + sc;
        vp0 = *(const uint4*)vr; vp1 = *(const uint4*)(vr + 8);
#pragma unroll
        for (int i = 0; i < 4; ++i) mc[i] = *(const f32x4*)(mrow + i * 16);
    }

    for (int kt = 0; kt < 16; ++kt) {
        __syncthreads();    // prior iteration's LDS reads complete
        *(uint4*)&Ks[srow * 72 + sc]     = kp0;
        *(uint4*)&Ks[srow * 72 + sc + 8] = kp1;
        *(uint4*)&Vs[srow * 72 + sc]     = vp0;
        *(uint4*)&Vs[srow * 72 + sc + 8] = vp1;
        __syncthreads();    // staging visible

        // prefetch kt+1 (overlaps compute)
        if (kt < 15) {
            int nk = (kt + 1) * 64;
            const u16* kr = kbase + (size_t)(nk + srow) * HD + sc;
            kp0 = *(const uint4*)kr; kp1 = *(const uint4*)(kr + 8);
            const u16* vr = vtbase + (size_t)srow * S_LEN + nk + sc;
            vp0 = *(const uint4*)vr; vp1 = *(const uint4*)(vr + 8);
            const float* mr = mrow + nk;
#pragma unroll
            for (int i = 0; i < 4; ++i) mn[i] = *(const f32x4*)(mr + i * 16);
        }

        // S^T = K * Q^T : A = K tile rows (keys), B = Q regs
#pragma unroll
        for (int mt = 0; mt < 4; ++mt) {
            bf16x8 af0 = *(const bf16x8*)&Ks[(mt * 16 + l16) * 72 + quad * 8];
            bf16x8 af1 = *(const bf16x8*)&Ks[(mt * 16 + l16) * 72 + 32 + quad * 8];
            f32x4 z = (f32x4){0.f, 0.f, 0.f, 0.f};
            z = __builtin_amdgcn_mfma_f32_16x16x32_bf16(af0, qf0, z, 0, 0, 0);
            f32x4 s = __builtin_amdgcn_mfma_f32_16x16x32_bf16(af1, qf1, s = z, 0, 0, 0);

            // softmax: 4 consecutive keys for this lane's q; round-half-up pack
            u32 er[4];
#pragma unroll
            for (int rg = 0; rg < 4; ++rg) {
                float e = __expf(s[rg] * mc[mt][rg]);
                u32 u = __float_as_uint(e) + 0x8000u;
                er[rg] = u;
                l_part += __uint_as_float(u & 0xFFFF0000u);  // consistent with stored P
            }
            uint2 pk;
            pk.x = __builtin_amdgcn_perm(er[1], er[0], 0x07060302u);
            pk.y = __builtin_amdgcn_perm(er[3], er[2], 0x07060302u);
            *(uint2*)&Ps[q * 72 + mt * 16 + quad * 4] = pk;   // wave-private strip
        }
        // no barrier: P strips are wave-private; in-wave DS ordering + lgkmcnt suffice

        // PV: O = P * V  (A = P fragments, B = V^T tiles)
        bf16x8 pf0 = *(const bf16x8*)&Ps[q * 72 + quad * 8];
        bf16x8 pf1 = *(const bf16x8*)&Ps[q * 72 + 32 + quad * 8];
#pragma unroll
        for (int nt = 0; nt < 4; ++nt) {
            bf16x8 vf0 = *(const bf16x8*)&Vs[(nt * 16 + l16) * 72 + quad * 8];
            bf16x8 vf1 = *(const bf16x8*)&Vs[(nt * 16 + l16) * 72 + 32 + quad * 8];
            o_acc[nt] = __builtin_amdgcn_mfma_f32_16x16x32_bf16(pf0, vf0, o_acc[nt], 0, 0, 0);
            o_acc[nt] = __builtin_amdgcn_mfma_f32_16x16x32_bf16(pf1, vf1, o_acc[nt], 0, 0, 0);
        }
        // rotate mask prefetch
#pragma unroll
        for (int i = 0; i < 4; ++i) mc[i] = mn[i];
    }

    // final l reduction: sum across quads (lanes with same l16), then in-wave transpose
    l_part += __shfl_xor(l_part, 16);
    l_part += __shfl_xor(l_part, 32);
    l_lds[w * 16 + l16] = l_part;        // wave-private strip write
    // read pattern below is same-wave; compiler orders DS ops

#pragma unroll
    for (int reg = 0; reg < 4; ++reg) {
        int row = w * 16 + quad * 4 + reg;
        float inv = 1.0f / l_lds[row];
        int sidx = s0 + row;
        u16* dst = aout + ((size_t)(b * S_LEN + sidx)) * HID + (g * R_REP + r) * HD;
#pragma unroll
        for (int nt = 0; nt < 4; ++nt)
            dst[nt * 16 + l16] = f2bf(o_acc[nt][reg] * inv);
    }
}

// ------- Output GEMM: BM=64 BN=128 BK=64, 512 blocks (2/CU); dbuf, one barrier
//         per K64-step; fp32 out + bias + residual -------
__global__ __launch_bounds__(256) void gemm_o(const u16* __restrict__ A,
                                              const u16* __restrict__ WT,
                                              const float* __restrict__ bo,
                                              const float* __restrict__ Xres,
                                              float* __restrict__ out) {
    __shared__ __align__(16) u16 As[2][64 * 64];
    __shared__ __align__(16) u16 Bs[2][128 * 64];
    int tid = threadIdx.x;
    int w = tid >> 6, lane = tid & 63, quad = lane >> 4, l16 = lane & 15;
    int m0 = blockIdx.y * 64, n0 = blockIdx.x * 128;
    int wr = (w >> 1) * 32, wc = (w & 1) * 64;
    int srow = lane >> 3, scol = (lane & 7) * 8;

    const u16* aP0 = &A[(size_t)(m0 + w * 16 + srow) * 2048 + scol];
    const u16* aP1 = aP0 + (size_t)8 * 2048;
    const u16* bP  = &WT[(size_t)(n0 + w * 32 + srow) * 2048 + scol];

    f32x4 acc[2][4];
#pragma unroll
    for (int i = 0; i < 2; ++i)
#pragma unroll
        for (int j = 0; j < 4; ++j) acc[i][j] = (f32x4){0.f, 0.f, 0.f, 0.f};

    gload_lds16(aP0, &As[0][(w * 16) * 64]);
    gload_lds16(aP1, &As[0][(w * 16 + 8) * 64]);
#pragma unroll
    for (int j = 0; j < 4; ++j)
        gload_lds16(bP + (size_t)(j * 8) * 2048, &Bs[0][(w * 32 + j * 8) * 64]);
    __syncthreads();

    int cur = 0;
    for (int k0 = 0; k0 < 2048; k0 += 64) {
        int kn = k0 + 64;
        if (kn < 2048) {
            gload_lds16(aP0 + kn, &As[cur ^ 1][(w * 16) * 64]);
            gload_lds16(aP1 + kn, &As[cur ^ 1][(w * 16 + 8) * 64]);
#pragma unroll
            for (int j = 0; j < 4; ++j)
                gload_lds16(bP + (size_t)(j * 8) * 2048 + kn, &Bs[cur ^ 1][(w * 32 + j * 8) * 64]);
        }
#pragma unroll
        for (int kk = 0; kk < 2; ++kk) {
            bf16x8 af[2], bfr[4];
#pragma unroll
            for (int mt = 0; mt < 2; ++mt)
                af[mt] = *(const bf16x8*)&As[cur][(wr + mt * 16 + l16) * 64 + kk * 32 + quad * 8];
#pragma unroll
            for (int nt = 0; nt < 4; ++nt)
                bfr[nt] = *(const bf16x8*)&Bs[cur][(wc + nt * 16 + l16) * 64 + kk * 32 + quad * 8];
#pragma unroll
            for (int mt = 0; mt < 2; ++mt)
#pragma unroll
                for (int nt = 0; nt < 4; ++nt)
                    acc[mt][nt] = __builtin_amdgcn_mfma_f32_16x16x32_bf16(af[mt], bfr[nt], acc[mt][nt], 0, 0, 0);
        }
        __syncthreads();
        cur ^= 1;
    }

#pragma unroll
    for (int nt = 0; nt < 4; ++nt) {
        int n = n0 + wc + nt * 16 + l16;
        float bias = bo[n];
#pragma unroll
        for (int mt = 0; mt < 2; ++mt) {
#pragma unroll
            for (int reg = 0; reg < 4; ++reg) {
                int m = m0 + wr + mt * 16 + quad * 4 + reg;
                out[(size_t)m * 2048 + n] = acc[mt][nt][reg] + bias + Xres[(size_t)m * 2048 + n];
            }
        }
    }
}

extern "C" void kernel_launch(void* const* d_in, const int* in_sizes, int n_in,
                              void* d_out, int out_size, void* d_ws, size_t ws_size,
                              hipStream_t stream) {
    const float* x    = (const float*)d_in[0];
    const float* mask = (const float*)d_in[1];
    const float* Wq   = (const float*)d_in[2];
    const float* bq   = (const float*)d_in[3];
    const float* Wk   = (const float*)d_in[4];
    const float* bk   = (const float*)d_in[5];
    const float* Wv   = (const float*)d_in[6];
    const float* bv   = (const float*)d_in[7];
    const float* Wo   = (const float*)d_in[8];
    const float* bo   = (const float*)d_in[9];
    float* out = (float*)d_out;

    u16* ws = (u16*)d_ws;
    size_t off = 0;
    u16* WqkvT = ws + off; off += (size_t)NQKV * 2048;
    u16* WoT   = ws + off; off += (size_t)2048 * 2048;
    u16* q_buf = ws + off; off += (size_t)BATCH * G_KV * R_REP * S_LEN * HD;
    u16* k_buf = ws + off; off += (size_t)BATCH * G_KV * S_LEN * HD;
    u16* v_buf = ws + off; off += (size_t)BATCH * G_KV * S_LEN * HD;  // transposed [b][g][d][s]
    u16* a_out = ws + off; off += (size_t)2048 * 2048;
    u16* Xb    = a_out;   // alias: consumed by gemm_qkv before attn writes a_out

    prep<<<dim3(12288), 256, 0, stream>>>(x, Wq, Wk, Wv, Wo, Xb, WqkvT, WoT);

    gemm_qkv<<<dim3(NQKV / 128, 2048 / 64), 256, 0, stream>>>(Xb, WqkvT, bq, bk, bv,
                                                              q_buf, k_buf, v_buf);

    attn_mfma<<<dim3(BATCH * G_KV * R_REP * (S_LEN / 64)), 256, 0, stream>>>(
        q_buf, k_buf, v_buf, mask, a_out);

    gemm_o<<<dim3(2048 / 128, 2048 / 64), 256, 0, stream>>>(a_out, WoT, bo, x, out);
}

// Round 8
// 235.530 us; speedup vs baseline: 1.0730x; 1.0730x over previous
//
#include <hip/hip_runtime.h>

typedef unsigned short u16;
typedef unsigned int u32;
typedef __attribute__((ext_vector_type(8))) short bf16x8;
typedef __attribute__((ext_vector_type(4))) float f32x4;

#define HID 2048
#define S_LEN 1024
#define BATCH 2
#define G_KV 8
#define R_REP 4
#define HD 64
#define NQKV 3072  // 2048 q + 512 k + 512 v

__device__ __forceinline__ u16 f2bf(float f) {
    union { u32 u; float ff; } x; x.ff = f;
    u32 u = x.u;
    u += 0x7FFFu + ((u >> 16) & 1u);
    return (u16)(u >> 16);
}

__device__ __forceinline__ void gload_lds16(const void* g, void* l) {
    __builtin_amdgcn_global_load_lds((const __attribute__((address_space(1))) void*)g,
                                     (__attribute__((address_space(3))) void*)l,
                                     16, 0, 0);
}

// ------- Fused prep: cvt_x | transpose_qkv | transpose_cvt(Wo) in one launch -------
__global__ __launch_bounds__(256) void prep(const float* __restrict__ x,
                                            const float* __restrict__ Wq,
                                            const float* __restrict__ Wk,
                                            const float* __restrict__ Wv,
                                            const float* __restrict__ Wo,
                                            u16* __restrict__ Xb,
                                            u16* __restrict__ WqkvT,
                                            u16* __restrict__ WoT) {
    __shared__ float tile[32][33];
    int bid = blockIdx.x, tid = threadIdx.x;

    if (bid < 2048) {
        int i = (bid * 256 + tid) * 8;
        float4 a = *(const float4*)(x + i);
        float4 b = *(const float4*)(x + i + 4);
        u16 t[8] = {f2bf(a.x), f2bf(a.y), f2bf(a.z), f2bf(a.w),
                    f2bf(b.x), f2bf(b.y), f2bf(b.z), f2bf(b.w)};
        *(uint4*)(Xb + i) = *(const uint4*)t;
        return;
    }

    int tx = tid & 31, ty = tid >> 5;
    if (bid < 8192) {
        int local = bid - 2048;
        int n0 = (local % 96) * 32, k0 = (local / 96) * 32;
        const float* in; int N, nc0;
        if (n0 < 2048)      { in = Wq; N = 2048; nc0 = n0; }
        else if (n0 < 2560) { in = Wk; N = 512;  nc0 = n0 - 2048; }
        else                { in = Wv; N = 512;  nc0 = n0 - 2560; }
#pragma unroll
        for (int j = 0; j < 4; ++j)
            tile[ty + j * 8][tx] = in[(size_t)(k0 + ty + j * 8) * N + nc0 + tx];
        __syncthreads();
#pragma unroll
        for (int j = 0; j < 4; ++j)
            WqkvT[(size_t)(n0 + ty + j * 8) * 2048 + k0 + tx] = f2bf(tile[tx][ty + j * 8]);
        return;
    }

    {
        int local = bid - 8192;
        int n0 = (local & 63) * 32, k0 = (local >> 6) * 32;
#pragma unroll
        for (int j = 0; j < 4; ++j)
            tile[ty + j * 8][tx] = Wo[(size_t)(k0 + ty + j * 8) * 2048 + n0 + tx];
        __syncthreads();
#pragma unroll
        for (int j = 0; j < 4; ++j)
            WoT[(size_t)(n0 + ty + j * 8) * 2048 + k0 + tx] = f2bf(tile[tx][ty + j * 8]);
    }
}

// ------- QKV GEMM: BM=64 BN=128 BK=32, 768 blocks (3/CU); R1-exact (best: 53.6us) -------
__global__ __launch_bounds__(256) void gemm_qkv(const u16* __restrict__ Xb,
                                                const u16* __restrict__ WT,
                                                const float* __restrict__ bq,
                                                const float* __restrict__ bk,
                                                const float* __restrict__ bv,
                                                u16* __restrict__ qb,
                                                u16* __restrict__ kb,
                                                u16* __restrict__ vb) {
    __shared__ __align__(16) u16 As[2][64 * 32];
    __shared__ __align__(16) u16 Bs[2][128 * 32];
    int tid = threadIdx.x;
    int w = tid >> 6, lane = tid & 63, quad = lane >> 4, l16 = lane & 15;
    int m0 = blockIdx.y * 64, n0 = blockIdx.x * 128;
    int wr = (w >> 1) * 32, wc = (w & 1) * 64;   // wave tile 32x64
    int srow = lane >> 2, scol = (lane & 3) * 8;

    const u16* aP  = &Xb[(size_t)(m0 + w * 16 + srow) * 2048 + scol];
    const u16* bP0 = &WT[(size_t)(n0 + w * 32 + srow) * 2048 + scol];
    const u16* bP1 = &WT[(size_t)(n0 + w * 32 + 16 + srow) * 2048 + scol];

    f32x4 acc[2][4];
#pragma unroll
    for (int i = 0; i < 2; ++i)
#pragma unroll
        for (int j = 0; j < 4; ++j) acc[i][j] = (f32x4){0.f, 0.f, 0.f, 0.f};

    gload_lds16(aP,  &As[0][(w * 16) * 32]);
    gload_lds16(bP0, &Bs[0][(w * 32) * 32]);
    gload_lds16(bP1, &Bs[0][(w * 32 + 16) * 32]);
    __syncthreads();

    int cur = 0;
    for (int k0 = 0; k0 < 2048; k0 += 32) {
        int kn = k0 + 32;
        if (kn < 2048) {
            gload_lds16(aP + kn,  &As[cur ^ 1][(w * 16) * 32]);
            gload_lds16(bP0 + kn, &Bs[cur ^ 1][(w * 32) * 32]);
            gload_lds16(bP1 + kn, &Bs[cur ^ 1][(w * 32 + 16) * 32]);
        }
        bf16x8 af[2], bfr[4];
#pragma unroll
        for (int mt = 0; mt < 2; ++mt)
            af[mt] = *(const bf16x8*)&As[cur][(wr + mt * 16 + l16) * 32 + quad * 8];
#pragma unroll
        for (int nt = 0; nt < 4; ++nt)
            bfr[nt] = *(const bf16x8*)&Bs[cur][(wc + nt * 16 + l16) * 32 + quad * 8];
#pragma unroll
        for (int mt = 0; mt < 2; ++mt)
#pragma unroll
            for (int nt = 0; nt < 4; ++nt)
                acc[mt][nt] = __builtin_amdgcn_mfma_f32_16x16x32_bf16(af[mt], bfr[nt], acc[mt][nt], 0, 0, 0);
        __syncthreads();
        cur ^= 1;
    }

#pragma unroll
    for (int nt = 0; nt < 4; ++nt) {
        int n = n0 + wc + nt * 16 + l16;
        float bias;
        if (n < 2048) bias = bq[n];
        else if (n < 2560) bias = bk[n - 2048];
        else bias = bv[n - 2560];
#pragma unroll
        for (int mt = 0; mt < 2; ++mt) {
#pragma unroll
            for (int reg = 0; reg < 4; ++reg) {
                int m = m0 + wr + mt * 16 + quad * 4 + reg;
                float val = acc[mt][nt][reg] + bias;
                int b = m >> 10, s = m & 1023;
                if (n < 2048) {
                    int g = n >> 8, r = (n >> 6) & 3, d = n & 63;
                    qb[((((size_t)(b * G_KV + g) * R_REP + r) * S_LEN) + s) * HD + d] = f2bf(val * 0.125f);
                } else if (n < 2560) {
                    int n2 = n - 2048, g = n2 >> 6, d = n2 & 63;
                    kb[(((size_t)(b * G_KV + g) * S_LEN) + s) * HD + d] = f2bf(val);
                } else {
                    int n2 = n - 2560, g = n2 >> 6, d = n2 & 63;
                    vb[(((size_t)(b * G_KV + g) * HD + d) * S_LEN) + s] = f2bf(val);  // V^T
                }
            }
        }
    }
}

// ------- Attention v2: wave = head. Block covers 4 heads x 16 q-rows of one (b,g).
//         K/V staged once for all 4 heads; mask tile (16q x 64k) staged in LDS,
//         shared by 4 waves: mask global traffic /4 (256 -> 64 MB), coalesced. -------
__global__ __launch_bounds__(256) void attn_mfma(const u16* __restrict__ qbuf,
                                                 const u16* __restrict__ kbuf,
                                                 const u16* __restrict__ vtbuf,
                                                 const float* __restrict__ mask,
                                                 u16* __restrict__ aout) {
    __shared__ __align__(16) u16 Ks[64 * 72];   // [key][dim]
    __shared__ __align__(16) u16 Vs[64 * 72];   // [dim][key]
    __shared__ __align__(16) u16 Ps[64 * 72];   // [wave-strip q][key] bf16
    __shared__ __align__(16) float Ms[16 * 68]; // [q-local][key] fp32, pad 68
    __shared__ float l_lds[64];

    int d = blockIdx.x;                   // 1024 = B*G*64
    int qblk = d & 63, g = (d >> 6) & 7, b = d >> 9;
    int s0 = qblk * 16;

    int tid = threadIdx.x;
    int w = tid >> 6, lane = tid & 63, quad = lane >> 4, l16 = lane & 15;
    int qs = w * 16 + l16;                // wave-private strip row (head w, q-col l16)

    // Q: head r = w, rows s0..s0+15; lane's q-col = l16
    const u16* qrow = qbuf +
        ((((size_t)(b * G_KV + g) * R_REP + w) * S_LEN) + s0 + l16) * HD;
    bf16x8 qf0 = *(const bf16x8*)(qrow + quad * 8);
    bf16x8 qf1 = *(const bf16x8*)(qrow + 32 + quad * 8);

    f32x4 o_acc[4];
#pragma unroll
    for (int i = 0; i < 4; ++i) o_acc[i] = (f32x4){0.f, 0.f, 0.f, 0.f};
    float l_part = 0.f;

    const u16* kbase  = kbuf  + (size_t)(b * G_KV + g) * S_LEN * HD;
    const u16* vtbase = vtbuf + (size_t)(b * G_KV + g) * HD * S_LEN;
    // mask staging: thread t covers row (t>>4), floats (t&15)*4 .. +4 of the 64-key tile
    const float* mstage = mask + ((size_t)b * S_LEN + s0 + (tid >> 4)) * S_LEN + (tid & 15) * 4;
    int msrow = tid >> 4, mscol = (tid & 15) * 4;

    int srow = tid >> 2, sc = (tid & 3) * 16;

    // prologue: prefetch tile 0
    uint4 kp0, kp1, vp0, vp1;
    f32x4 mp;
    {
        const u16* kr = kbase + (size_t)srow * HD + sc;
        kp0 = *(const uint4*)kr; kp1 = *(const uint4*)(kr + 8);
        const u16* vr = vtbase + (size_t)srow * S_LEN + sc;
        vp0 = *(const uint4*)vr; vp1 = *(const uint4*)(vr + 8);
        mp = *(const f32x4*)mstage;
    }

    for (int kt = 0; kt < 16; ++kt) {
        __syncthreads();    // prior iteration's LDS reads complete
        *(uint4*)&Ks[srow * 72 + sc]     = kp0;
        *(uint4*)&Ks[srow * 72 + sc + 8] = kp1;
        *(uint4*)&Vs[srow * 72 + sc]     = vp0;
        *(uint4*)&Vs[srow * 72 + sc + 8] = vp1;
        *(f32x4*)&Ms[msrow * 68 + mscol] = mp;
        __syncthreads();    // staging visible

        // prefetch kt+1 (overlaps compute)
        if (kt < 15) {
            int nk = (kt + 1) * 64;
            const u16* kr = kbase + (size_t)(nk + srow) * HD + sc;
            kp0 = *(const uint4*)kr; kp1 = *(const uint4*)(kr + 8);
            const u16* vr = vtbase + (size_t)srow * S_LEN + nk + sc;
            vp0 = *(const uint4*)vr; vp1 = *(const uint4*)(vr + 8);
            mp = *(const f32x4*)(mstage + nk);
        }

        // S^T = K * Q^T : A = K tile rows (keys), B = Q regs
#pragma unroll
        for (int mt = 0; mt < 4; ++mt) {
            bf16x8 af0 = *(const bf16x8*)&Ks[(mt * 16 + l16) * 72 + quad * 8];
            bf16x8 af1 = *(const bf16x8*)&Ks[(mt * 16 + l16) * 72 + 32 + quad * 8];
            f32x4 z = (f32x4){0.f, 0.f, 0.f, 0.f};
            z = __builtin_amdgcn_mfma_f32_16x16x32_bf16(af0, qf0, z, 0, 0, 0);
            f32x4 s = __builtin_amdgcn_mfma_f32_16x16x32_bf16(af1, qf1, s = z, 0, 0, 0);

            // mask for (q=l16, keys mt*16+quad*4+rg) from shared tile
            f32x4 mv = *(const f32x4*)&Ms[l16 * 68 + mt * 16 + quad * 4];

            u32 er[4];
#pragma unroll
            for (int rg = 0; rg < 4; ++rg) {
                float e = __expf(s[rg] * mv[rg]);
                u32 u = __float_as_uint(e) + 0x8000u;
                er[rg] = u;
                l_part += __uint_as_float(u & 0xFFFF0000u);
            }
            uint2 pk;
            pk.x = __builtin_amdgcn_perm(er[1], er[0], 0x07060302u);
            pk.y = __builtin_amdgcn_perm(er[3], er[2], 0x07060302u);
            *(uint2*)&Ps[qs * 72 + mt * 16 + quad * 4] = pk;   // wave-private strip
        }
        // no barrier: P strips are wave-private

        // PV: O = P * V
        bf16x8 pf0 = *(const bf16x8*)&Ps[qs * 72 + quad * 8];
        bf16x8 pf1 = *(const bf16x8*)&Ps[qs * 72 + 32 + quad * 8];
#pragma unroll
        for (int nt = 0; nt < 4; ++nt) {
            bf16x8 vf0 = *(const bf16x8*)&Vs[(nt * 16 + l16) * 72 + quad * 8];
            bf16x8 vf1 = *(const bf16x8*)&Vs[(nt * 16 + l16) * 72 + 32 + quad * 8];
            o_acc[nt] = __builtin_amdgcn_mfma_f32_16x16x32_bf16(pf0, vf0, o_acc[nt], 0, 0, 0);
            o_acc[nt] = __builtin_amdgcn_mfma_f32_16x16x32_bf16(pf1, vf1, o_acc[nt], 0, 0, 0);
        }
    }

    // l reduction across quads (same l16), then per-row normalize
    l_part += __shfl_xor(l_part, 16);
    l_part += __shfl_xor(l_part, 32);
    l_lds[w * 16 + l16] = l_part;

#pragma unroll
    for (int reg = 0; reg < 4; ++reg) {
        int qloc = quad * 4 + reg;               // local q row
        float inv = 1.0f / l_lds[w * 16 + qloc];
        u16* dst = aout + ((size_t)(b * S_LEN + s0 + qloc)) * HID + (g * R_REP + w) * HD;
#pragma unroll
        for (int nt = 0; nt < 4; ++nt)
            dst[nt * 16 + l16] = f2bf(o_acc[nt][reg] * inv);
    }
}

// ------- Output GEMM: BM=64 BN=128 BK=32, 512 blocks (2/CU); R1-exact -------
__global__ __launch_bounds__(256) void gemm_o(const u16* __restrict__ A,
                                              const u16* __restrict__ WT,
                                              const float* __restrict__ bo,
                                              const float* __restrict__ Xres,
                                              float* __restrict__ out) {
    __shared__ __align__(16) u16 As[2][64 * 32];
    __shared__ __align__(16) u16 Bs[2][128 * 32];
    int tid = threadIdx.x;
    int w = tid >> 6, lane = tid & 63, quad = lane >> 4, l16 = lane & 15;
    int m0 = blockIdx.y * 64, n0 = blockIdx.x * 128;
    int wr = (w >> 1) * 32, wc = (w & 1) * 64;
    int srow = lane >> 2, scol = (lane & 3) * 8;

    const u16* aP  = &A[(size_t)(m0 + w * 16 + srow) * 2048 + scol];
    const u16* bP0 = &WT[(size_t)(n0 + w * 32 + srow) * 2048 + scol];
    const u16* bP1 = &WT[(size_t)(n0 + w * 32 + 16 + srow) * 2048 + scol];

    f32x4 acc[2][4];
#pragma unroll
    for (int i = 0; i < 2; ++i)
#pragma unroll
        for (int j = 0; j < 4; ++j) acc[i][j] = (f32x4){0.f, 0.f, 0.f, 0.f};

    gload_lds16(aP,  &As[0][(w * 16) * 32]);
    gload_lds16(bP0, &Bs[0][(w * 32) * 32]);
    gload_lds16(bP1, &Bs[0][(w * 32 + 16) * 32]);
    __syncthreads();

    int cur = 0;
    for (int k0 = 0; k0 < 2048; k0 += 32) {
        int kn = k0 + 32;
        if (kn < 2048) {
            gload_lds16(aP + kn,  &As[cur ^ 1][(w * 16) * 32]);
            gload_lds16(bP0 + kn, &Bs[cur ^ 1][(w * 32) * 32]);
            gload_lds16(bP1 + kn, &Bs[cur ^ 1][(w * 32 + 16) * 32]);
        }
        bf16x8 af[2], bfr[4];
#pragma unroll
        for (int mt = 0; mt < 2; ++mt)
            af[mt] = *(const bf16x8*)&As[cur][(wr + mt * 16 + l16) * 32 + quad * 8];
#pragma unroll
        for (int nt = 0; nt < 4; ++nt)
            bfr[nt] = *(const bf16x8*)&Bs[cur][(wc + nt * 16 + l16) * 32 + quad * 8];
#pragma unroll
        for (int mt = 0; mt < 2; ++mt)
#pragma unroll
            for (int nt = 0; nt < 4; ++nt)
                acc[mt][nt] = __builtin_amdgcn_mfma_f32_16x16x32_bf16(af[mt], bfr[nt], acc[mt][nt], 0, 0, 0);
        __syncthreads();
        cur ^= 1;
    }

#pragma unroll
    for (int nt = 0; nt < 4; ++nt) {
        int n = n0 + wc + nt * 16 + l16;
        float bias = bo[n];
#pragma unroll
        for (int mt = 0; mt < 2; ++mt) {
#pragma unroll
            for (int reg = 0; reg < 4; ++reg) {
                int m = m0 + wr + mt * 16 + quad * 4 + reg;
                out[(size_t)m * 2048 + n] = acc[mt][nt][reg] + bias + Xres[(size_t)m * 2048 + n];
            }
        }
    }
}

extern "C" void kernel_launch(void* const* d_in, const int* in_sizes, int n_in,
                              void* d_out, int out_size, void* d_ws, size_t ws_size,
                              hipStream_t stream) {
    const float* x    = (const float*)d_in[0];
    const float* mask = (const float*)d_in[1];
    const float* Wq   = (const float*)d_in[2];
    const float* bq   = (const float*)d_in[3];
    const float* Wk   = (const float*)d_in[4];
    const float* bk   = (const float*)d_in[5];
    const float* Wv   = (const float*)d_in[6];
    const float* bv   = (const float*)d_in[7];
    const float* Wo   = (const float*)d_in[8];
    const float* bo   = (const float*)d_in[9];
    float* out = (float*)d_out;

    u16* ws = (u16*)d_ws;
    size_t off = 0;
    u16* WqkvT = ws + off; off += (size_t)NQKV * 2048;
    u16* WoT   = ws + off; off += (size_t)2048 * 2048;
    u16* q_buf = ws + off; off += (size_t)BATCH * G_KV * R_REP * S_LEN * HD;
    u16* k_buf = ws + off; off += (size_t)BATCH * G_KV * S_LEN * HD;
    u16* v_buf = ws + off; off += (size_t)BATCH * G_KV * S_LEN * HD;  // V^T [b][g][d][s]
    u16* a_out = ws + off; off += (size_t)2048 * 2048;
    u16* Xb    = a_out;   // alias: consumed by gemm_qkv before attn writes a_out

    prep<<<dim3(12288), 256, 0, stream>>>(x, Wq, Wk, Wv, Wo, Xb, WqkvT, WoT);

    gemm_qkv<<<dim3(NQKV / 128, 2048 / 64), 256, 0, stream>>>(Xb, WqkvT, bq, bk, bv,
                                                              q_buf, k_buf, v_buf);

    attn_mfma<<<dim3(BATCH * G_KV * 64), 256, 0, stream>>>(
        q_buf, k_buf, v_buf, mask, a_out);

    gemm_o<<<dim3(2048 / 128, 2048 / 64), 256, 0, stream>>>(a_out, WoT, bo, x, out);
}